// Round 2
// baseline (225.450 us; speedup 1.0000x reference)
//
#include <hip/hip_runtime.h>
#include <cstdint>
#include <cstddef>

#define NN 8192
#define ATOMF 64
#define HID 128
#define HEADS 8
#define NG 256
#define ELLW 192
#define NEGSLOPE 0.2f

// ---- build ELL edge list from dense adj (one HBM pass, values held in regs) ----
__global__ __launch_bounds__(256) void k_build_ell(const float* __restrict__ adj,
                                                   int* __restrict__ ell,
                                                   int* __restrict__ deg) {
    int row = blockIdx.x;
    int t = threadIdx.x;
    int lane = t & 63, wid = t >> 6;
    const float4* a4 = (const float4*)(adj + (size_t)row * NN);
    float4 v[8];
    int c = 0;
    #pragma unroll
    for (int it = 0; it < 8; ++it) {
        v[it] = a4[it * 256 + t];
        c += (v[it].x > 0.f) + (v[it].y > 0.f) + (v[it].z > 0.f) + (v[it].w > 0.f);
    }
    // wave-level inclusive scan of counts (no barriers)
    int s = c;
    #pragma unroll
    for (int o = 1; o < 64; o <<= 1) {
        int u = __shfl_up(s, o);
        if (lane >= o) s += u;
    }
    __shared__ int wtot[4];
    if (lane == 63) wtot[wid] = s;
    __syncthreads();
    int offs = 0;
    #pragma unroll
    for (int w = 0; w < 4; ++w) offs += (w < wid) ? wtot[w] : 0;
    int total = wtot[0] + wtot[1] + wtot[2] + wtot[3];
    int pos = offs + s - c;          // exclusive prefix, deterministic order

    __shared__ int jls[ELLW];
    #pragma unroll
    for (int it = 0; it < 8; ++it) {
        int j0 = (it * 256 + t) * 4;
        if (v[it].x > 0.f && pos < ELLW) { jls[pos] = j0;     ++pos; }
        if (v[it].y > 0.f && pos < ELLW) { jls[pos] = j0 + 1; ++pos; }
        if (v[it].z > 0.f && pos < ELLW) { jls[pos] = j0 + 2; ++pos; }
        if (v[it].w > 0.f && pos < ELLW) { jls[pos] = j0 + 3; ++pos; }
    }
    __syncthreads();
    int tot = total < ELLW ? total : ELLW;
    int* er = ell + (size_t)row * ELLW;
    for (int k = t; k < tot; k += 256) er[k] = jls[k];   // coalesced
    if (t == 0) deg[row] = tot;
}

// ---- reduce W1,W2 [1024,128] over their 8 row-blocks -> Wr [128,128] ----
__global__ __launch_bounds__(256) void k_wreduce(const float* __restrict__ W1,
                                                 const float* __restrict__ W2,
                                                 float* __restrict__ Wr1,
                                                 float* __restrict__ Wr2) {
    int b = blockIdx.x;
    const float* W = (b < 64) ? W1 : W2;
    float* Wr = (b < 64) ? Wr1 : Wr2;
    int i = (b & 63) * 256 + threadIdx.x;   // 0..16383
    int k = i >> 7, c = i & 127;
    float s = 0.f;
    #pragma unroll
    for (int h = 0; h < HEADS; ++h)
        s += W[(size_t)(h * HID + k) * HID + c];
    Wr[i] = s;
}

// ---- Y[N,128] = act(X[N,K]) @ W[K,128]  + fused attention scores ----
template<int K, bool RELU>
__global__ __launch_bounds__(256) void k_gemm_s(const float* __restrict__ X,
                                                const float* __restrict__ W,
                                                const float* __restrict__ asrc,
                                                const float* __restrict__ adst,
                                                float* __restrict__ Y,
                                                float* __restrict__ ssrc,
                                                float* __restrict__ sdst) {
    __shared__ float Xl[32 * K];
    __shared__ float partS[4][16], partD[4][16];
    int t = threadIdx.x;
    int lane = t & 63, w = t >> 6;
    int row0 = blockIdx.x * 32;
    for (int i = t; i < 32 * K; i += 256) {
        int r = i / K, k = i % K;
        float x = X[(size_t)(row0 + r) * K + k];
        Xl[i] = RELU ? fmaxf(x, 0.f) : x;
    }
    __syncthreads();
    int c = t & 127;
    int rh = t >> 7;                 // 0..1 -> rows rh*16 .. rh*16+15
    float acc[16];
    #pragma unroll
    for (int m = 0; m < 16; ++m) acc[m] = 0.f;
    for (int k = 0; k < K; ++k) {
        float wv = W[k * HID + c];   // coalesced, L2-resident
        #pragma unroll
        for (int m = 0; m < 16; ++m)
            acc[m] += Xl[(rh * 16 + m) * K + k] * wv;   // LDS broadcast
    }
    float as = asrc[c], ad = adst[c];
    #pragma unroll
    for (int m = 0; m < 16; ++m) {
        Y[(size_t)(row0 + rh * 16 + m) * HID + c] = acc[m];
        float ps = acc[m] * as, pd = acc[m] * ad;
        #pragma unroll
        for (int o = 32; o; o >>= 1) {
            ps += __shfl_xor(ps, o);
            pd += __shfl_xor(pd, o);
        }
        if (lane == 0) { partS[w][m] = ps; partD[w][m] = pd; }
    }
    __syncthreads();
    if (t < 32) {
        int r2 = t >> 4, m = t & 15;
        ssrc[row0 + t] = partS[2 * r2][m] + partS[2 * r2 + 1][m];
        sdst[row0 + t] = partD[2 * r2][m] + partD[2 * r2 + 1][m];
    }
}

// ---- sparse masked softmax + aggregation: out[i] = sum_j attn_ij * h[j] ----
// 4 rows per block, one wave per row, no cross-wave barriers.
__global__ __launch_bounds__(256) void k_agg(const float* __restrict__ h,
                                             const float* __restrict__ ssrc,
                                             const float* __restrict__ sdst,
                                             const int* __restrict__ ell,
                                             const int* __restrict__ deg,
                                             float* __restrict__ out) {
    __shared__ float wl[4][ELLW];
    __shared__ int jl[4][ELLW];
    int wid = threadIdx.x >> 6;
    int l = threadIdx.x & 63;
    int row = blockIdx.x * 4 + wid;
    int d = deg[row];
    float si = ssrc[row];
    const int* er = ell + (size_t)row * ELLW;
    // phase A: e_ij = leakyrelu(src_i + dst_j), running max
    float m = -1e30f;
    for (int k = l; k < d; k += 64) {
        int j = er[k];
        float e = si + sdst[j];
        e = e > 0.f ? e : NEGSLOPE * e;
        jl[wid][k] = j; wl[wid][k] = e;
        m = fmaxf(m, e);
    }
    #pragma unroll
    for (int o = 32; o; o >>= 1) m = fmaxf(m, __shfl_xor(m, o));
    // phase B: w = exp(e - m), denom
    float s = 0.f;
    for (int k = l; k < d; k += 64) {
        float w = __expf(wl[wid][k] - m);
        wl[wid][k] = w;
        s += w;
    }
    #pragma unroll
    for (int o = 32; o; o >>= 1) s += __shfl_xor(s, o);
    float inv = 1.f / s;
    // phase C: weighted gather-sum; lane owns dims 2l, 2l+1. 4x unroll for MLP.
    float a0 = 0.f, a1 = 0.f;
    const float* h2l = h + 2 * l;
    int k = 0;
    for (; k + 4 <= d; k += 4) {
        int j0 = jl[wid][k], j1 = jl[wid][k + 1], j2 = jl[wid][k + 2], j3 = jl[wid][k + 3];
        float w0 = wl[wid][k], w1 = wl[wid][k + 1], w2 = wl[wid][k + 2], w3 = wl[wid][k + 3];
        float2 v0 = *(const float2*)(h2l + (size_t)j0 * HID);
        float2 v1 = *(const float2*)(h2l + (size_t)j1 * HID);
        float2 v2 = *(const float2*)(h2l + (size_t)j2 * HID);
        float2 v3 = *(const float2*)(h2l + (size_t)j3 * HID);
        a0 += w0 * v0.x; a1 += w0 * v0.y;
        a0 += w1 * v1.x; a1 += w1 * v1.y;
        a0 += w2 * v2.x; a1 += w2 * v2.y;
        a0 += w3 * v3.x; a1 += w3 * v3.y;
    }
    for (; k < d; ++k) {
        int j = jl[wid][k];
        float w = wl[wid][k];
        float2 v = *(const float2*)(h2l + (size_t)j * HID);
        a0 += w * v.x; a1 += w * v.y;
    }
    float2 o2; o2.x = a0 * inv; o2.y = a1 * inv;
    *(float2*)(out + (size_t)row * HID + 2 * l) = o2;
}

// ---- fused pool + fc: batch is sorted, block b owns graphs [8b, 8b+8) ----
__global__ __launch_bounds__(256) void k_poolfc(const float* __restrict__ h,
                                                const int* __restrict__ batch,
                                                const float* __restrict__ fcw,
                                                const float* __restrict__ fcb,
                                                float* __restrict__ out) {
    __shared__ float lsum[8];
    __shared__ int lcnt[8];
    int t = threadIdx.x;
    int b = blockIdx.x;
    int g0 = b * 8;
    if (t < 8) { lsum[t] = 0.f; lcnt[t] = 0; }
    // lower_bound for g0 and g0+8 over sorted batch
    int lo = 0, hi = NN;
    for (int it = 0; it < 13; ++it) {
        int mid = (lo + hi) >> 1;
        if (batch[mid] < g0) lo = mid + 1; else hi = mid;
    }
    int lo2 = lo, hi2 = NN;
    {
        int a = lo, bb = NN;
        for (int it = 0; it < 13; ++it) {
            int mid = (a + bb) >> 1;
            if (batch[mid] < g0 + 8) a = mid + 1; else bb = mid;
        }
        lo2 = lo; hi2 = a;
    }
    __syncthreads();
    int wid = t >> 6, lane = t & 63;
    for (int r = lo2 + wid; r < hi2; r += 4) {
        const float* hr = h + (size_t)r * HID;
        float p = hr[lane] * fcw[lane] + hr[lane + 64] * fcw[lane + 64];
        #pragma unroll
        for (int o = 32; o; o >>= 1) p += __shfl_xor(p, o);
        if (lane == 0) {
            int g = batch[r] - g0;
            atomicAdd(&lsum[g], p);
            atomicAdd(&lcnt[g], 1);
        }
    }
    __syncthreads();
    if (t < 8) out[g0 + t] = lsum[t] / fmaxf((float)lcnt[t], 1.f) + fcb[0];
}

extern "C" void kernel_launch(void* const* d_in, const int* in_sizes, int n_in,
                              void* d_out, int out_size, void* d_ws, size_t ws_size,
                              hipStream_t stream) {
    const float* x    = (const float*)d_in[0];
    const float* adj  = (const float*)d_in[1];
    const int*   batch= (const int*)  d_in[2];
    const float* W0   = (const float*)d_in[3];
    const float* a0s  = (const float*)d_in[4];
    const float* a0d  = (const float*)d_in[5];
    const float* W1   = (const float*)d_in[6];
    const float* a1s  = (const float*)d_in[7];
    const float* a1d  = (const float*)d_in[8];
    const float* W2   = (const float*)d_in[9];
    const float* a2s  = (const float*)d_in[10];
    const float* a2d  = (const float*)d_in[11];
    const float* fcw  = (const float*)d_in[12];
    const float* fcb  = (const float*)d_in[13];
    float* out = (float*)d_out;

    char* ws = (char*)d_ws;
    size_t off = 0;
    auto alloc = [&](size_t bytes) {
        char* p = ws + off;
        off = (off + bytes + 255) & ~255UL;
        return p;
    };
    int*   ell  = (int*)  alloc((size_t)NN * ELLW * 4);   // 6.3 MB
    int*   deg  = (int*)  alloc((size_t)NN * 4);
    float* hA   = (float*)alloc((size_t)NN * HID * 4);    // 4 MB
    float* hB   = (float*)alloc((size_t)NN * HID * 4);    // 4 MB
    float* ssrc = (float*)alloc((size_t)NN * 4);
    float* sdst = (float*)alloc((size_t)NN * 4);
    float* Wr1  = (float*)alloc((size_t)HID * HID * 4);
    float* Wr2  = (float*)alloc((size_t)HID * HID * 4);
    (void)ws_size; (void)in_sizes; (void)n_in; (void)out_size;

    k_build_ell<<<NN, 256, 0, stream>>>(adj, ell, deg);
    k_wreduce<<<128, 256, 0, stream>>>(W1, W2, Wr1, Wr2);

    // layer 0
    k_gemm_s<ATOMF, false><<<NN / 32, 256, 0, stream>>>(x, W0, a0s, a0d, hA, ssrc, sdst);
    k_agg<<<NN / 4, 256, 0, stream>>>(hA, ssrc, sdst, ell, deg, hB);
    // layer 1 (tile+relu collapses to relu(h) @ Wr1)
    k_gemm_s<HID, true><<<NN / 32, 256, 0, stream>>>(hB, Wr1, a1s, a1d, hA, ssrc, sdst);
    k_agg<<<NN / 4, 256, 0, stream>>>(hA, ssrc, sdst, ell, deg, hB);
    // layer 2
    k_gemm_s<HID, true><<<NN / 32, 256, 0, stream>>>(hB, Wr2, a2s, a2d, hA, ssrc, sdst);
    k_agg<<<NN / 4, 256, 0, stream>>>(hA, ssrc, sdst, ell, deg, hB);

    // fused global mean pool + fc
    k_poolfc<<<NG / 8, 256, 0, stream>>>(hB, batch, fcw, fcb, out);
}